// Round 1
// baseline (589.022 us; speedup 1.0000x reference)
//
#include <hip/hip_runtime.h>

// InvariantMessagePassingTP: out[n,lm,c] = sum_{e: recv[e]==n}
//   node_feats[sender[e],c] * edge_attrs[e,lm] * tp_weights[e, L_OF_LM[lm], c]
// N=10000 nodes, E=200000 edges, 16 lm, 4 l, 128 channels.
// receiver_list is SORTED -> contiguous segments -> one block per node,
// binary-search segment bounds, register accumulate, single write. No atomics.

#define N_NODES  10000
#define N_EDGES  200000
#define CHANNELS 128

__global__ __launch_bounds__(128) void imp_tp_kernel(
    const float* __restrict__ node_feats,    // (N, 128)
    const float* __restrict__ edge_attrs,    // (E, 16)
    const float* __restrict__ tp_weights,    // (E, 4, 128)
    const int*   __restrict__ sender_list,   // (E)
    const int*   __restrict__ receiver_list, // (E), sorted ascending
    float* __restrict__ out)                 // (N, 16, 128)
{
    const int n = blockIdx.x;
    const int c = threadIdx.x;

    // lower_bound(recv, n) and lower_bound(recv, n+1) — wave-uniform, cached.
    int lo = 0, hi = N_EDGES;
    while (lo < hi) { int mid = (lo + hi) >> 1; if (receiver_list[mid] < n)     lo = mid + 1; else hi = mid; }
    const int seg_start = lo;
    hi = N_EDGES;
    while (lo < hi) { int mid = (lo + hi) >> 1; if (receiver_list[mid] < n + 1) lo = mid + 1; else hi = mid; }
    const int seg_end = lo;

    float acc[16];
    #pragma unroll
    for (int i = 0; i < 16; ++i) acc[i] = 0.0f;

    const float4* __restrict__ ea4 = (const float4*)edge_attrs;

    for (int e = seg_start; e < seg_end; ++e) {
        const int s = sender_list[e];
        const float sf = node_feats[(size_t)s * CHANNELS + c];

        const float* __restrict__ w = tp_weights + (size_t)e * 4 * CHANNELS + c;
        const float w0 = w[0 * CHANNELS];
        const float w1 = w[1 * CHANNELS];
        const float w2 = w[2 * CHANNELS];
        const float w3 = w[3 * CHANNELS];

        // edge_attrs row: 16 floats, uniform across the wave (broadcast loads).
        const float4 a0 = ea4[(size_t)e * 4 + 0];
        const float4 a1 = ea4[(size_t)e * 4 + 1];
        const float4 a2 = ea4[(size_t)e * 4 + 2];
        const float4 a3 = ea4[(size_t)e * 4 + 3];

        // Factor per-l products once; L_OF_LM = [0, 1,1,1, 2,2,2,2,2, 3,3,3,3,3,3,3]
        const float p0 = sf * w0;
        const float p1 = sf * w1;
        const float p2 = sf * w2;
        const float p3 = sf * w3;

        acc[0]  = fmaf(p0, a0.x, acc[0]);
        acc[1]  = fmaf(p1, a0.y, acc[1]);
        acc[2]  = fmaf(p1, a0.z, acc[2]);
        acc[3]  = fmaf(p1, a0.w, acc[3]);
        acc[4]  = fmaf(p2, a1.x, acc[4]);
        acc[5]  = fmaf(p2, a1.y, acc[5]);
        acc[6]  = fmaf(p2, a1.z, acc[6]);
        acc[7]  = fmaf(p2, a1.w, acc[7]);
        acc[8]  = fmaf(p2, a2.x, acc[8]);
        acc[9]  = fmaf(p3, a2.y, acc[9]);
        acc[10] = fmaf(p3, a2.z, acc[10]);
        acc[11] = fmaf(p3, a2.w, acc[11]);
        acc[12] = fmaf(p3, a3.x, acc[12]);
        acc[13] = fmaf(p3, a3.y, acc[13]);
        acc[14] = fmaf(p3, a3.z, acc[14]);
        acc[15] = fmaf(p3, a3.w, acc[15]);
    }

    // One coalesced write per (lm) row; empty segments write zeros (d_out is
    // poisoned 0xAA before every launch, so every element must be written).
    float* __restrict__ o = out + (size_t)n * 16 * CHANNELS + c;
    #pragma unroll
    for (int lm = 0; lm < 16; ++lm) o[lm * CHANNELS] = acc[lm];
}

extern "C" void kernel_launch(void* const* d_in, const int* in_sizes, int n_in,
                              void* d_out, int out_size, void* d_ws, size_t ws_size,
                              hipStream_t stream) {
    const float* node_feats    = (const float*)d_in[0];
    const float* edge_attrs    = (const float*)d_in[1];
    const float* tp_weights    = (const float*)d_in[2];
    const int*   sender_list   = (const int*)d_in[3];
    const int*   receiver_list = (const int*)d_in[4];
    float* out = (float*)d_out;

    imp_tp_kernel<<<N_NODES, CHANNELS, 0, stream>>>(
        node_feats, edge_attrs, tp_weights, sender_list, receiver_list, out);
}

// Round 2
// 585.357 us; speedup vs baseline: 1.0063x; 1.0063x over previous
//
#include <hip/hip_runtime.h>

// InvariantMessagePassingTP: out[n,lm,c] = sum_{e: recv[e]==n}
//   node_feats[sender[e],c] * edge_attrs[e,lm] * tp_weights[e, L_OF_LM[lm], c]
// N=10000, E=200000, 16 lm -> 4 l, 128 channels. receiver_list sorted.
//
// v2: wave-per-node (64 lanes x float2 = 128 ch), float2 tp_weights loads
// (512 B/wave-instr), scalar (SGPR) path for e/sender/edge_attrs, 2-edge
// manual pipeline for MLP, segment bounds precomputed into d_ws.

#define N_NODES  10000
#define N_EDGES  200000

__global__ __launch_bounds__(256) void bounds_kernel(
    const int* __restrict__ recv, int* __restrict__ row_ptr)
{
    const int i = blockIdx.x * 256 + threadIdx.x;
    if (i > N_NODES) return;
    int lo = 0, hi = N_EDGES;
    while (lo < hi) { int mid = (lo + hi) >> 1; if (recv[mid] < i) lo = mid + 1; else hi = mid; }
    row_ptr[i] = lo;   // row_ptr[n] = lower_bound(recv, n); seg = [row_ptr[n], row_ptr[n+1])
}

struct Edge {
    float2 sf, w0, w1, w2, w3;
    float4 a0, a1, a2, a3;
};

#define FMA2(ac, p, s) do { (ac).x = fmaf((p).x, (s), (ac).x); (ac).y = fmaf((p).y, (s), (ac).y); } while (0)

__global__ __launch_bounds__(256) void imp_tp_kernel(
    const float* __restrict__ node_feats,    // (N, 128)
    const float* __restrict__ edge_attrs,    // (E, 16)
    const float* __restrict__ tp_weights,    // (E, 4, 128)
    const int*   __restrict__ sender_list,   // (E)
    const int*   __restrict__ row_ptr,       // (N+1)
    float* __restrict__ out)                 // (N, 16, 128)
{
    const int lane = threadIdx.x & 63;
    const int n    = blockIdx.x * 4 + (threadIdx.x >> 6);  // wave-per-node
    const int c    = lane * 2;                              // 2 channels/lane

    // Wave-uniform segment bounds -> SGPRs.
    const int lo = __builtin_amdgcn_readfirstlane(row_ptr[n]);
    const int hi = __builtin_amdgcn_readfirstlane(row_ptr[n + 1]);

    float2 acc[16];
    #pragma unroll
    for (int i = 0; i < 16; ++i) acc[i] = make_float2(0.f, 0.f);

    auto load_edge = [&](Edge& E, int e) {
        const int s = __builtin_amdgcn_readfirstlane(sender_list[e]);
        E.sf = *(const float2*)(node_feats + (size_t)s * 128 + c);
        const float* wp = tp_weights + (size_t)e * 512 + c;
        E.w0 = *(const float2*)(wp);
        E.w1 = *(const float2*)(wp + 128);
        E.w2 = *(const float2*)(wp + 256);
        E.w3 = *(const float2*)(wp + 384);
        const float4* ap = (const float4*)(edge_attrs + (size_t)e * 16);
        E.a0 = ap[0]; E.a1 = ap[1]; E.a2 = ap[2]; E.a3 = ap[3];
    };

    auto accum_edge = [&](const Edge& E) {
        float2 p0, p1, p2, p3;
        p0.x = E.sf.x * E.w0.x; p0.y = E.sf.y * E.w0.y;
        p1.x = E.sf.x * E.w1.x; p1.y = E.sf.y * E.w1.y;
        p2.x = E.sf.x * E.w2.x; p2.y = E.sf.y * E.w2.y;
        p3.x = E.sf.x * E.w3.x; p3.y = E.sf.y * E.w3.y;
        // L_OF_LM = [0, 1,1,1, 2,2,2,2,2, 3,3,3,3,3,3,3]
        FMA2(acc[0],  p0, E.a0.x);
        FMA2(acc[1],  p1, E.a0.y);
        FMA2(acc[2],  p1, E.a0.z);
        FMA2(acc[3],  p1, E.a0.w);
        FMA2(acc[4],  p2, E.a1.x);
        FMA2(acc[5],  p2, E.a1.y);
        FMA2(acc[6],  p2, E.a1.z);
        FMA2(acc[7],  p2, E.a1.w);
        FMA2(acc[8],  p2, E.a2.x);
        FMA2(acc[9],  p3, E.a2.y);
        FMA2(acc[10], p3, E.a2.z);
        FMA2(acc[11], p3, E.a2.w);
        FMA2(acc[12], p3, E.a3.x);
        FMA2(acc[13], p3, E.a3.y);
        FMA2(acc[14], p3, E.a3.z);
        FMA2(acc[15], p3, E.a3.w);
    };

    Edge A, B;
    int e = lo;
    for (; e + 1 < hi; e += 2) {   // 2 edges in flight: loads batched before computes
        load_edge(A, e);
        load_edge(B, e + 1);
        accum_edge(A);
        accum_edge(B);
    }
    if (e < hi) { load_edge(A, e); accum_edge(A); }

    // Coalesced 512 B stores per lm row; empty segments write zeros (d_out poisoned).
    float* __restrict__ o = out + (size_t)n * 2048 + c;
    #pragma unroll
    for (int lm = 0; lm < 16; ++lm) *(float2*)(o + lm * 128) = acc[lm];
}

extern "C" void kernel_launch(void* const* d_in, const int* in_sizes, int n_in,
                              void* d_out, int out_size, void* d_ws, size_t ws_size,
                              hipStream_t stream) {
    const float* node_feats    = (const float*)d_in[0];
    const float* edge_attrs    = (const float*)d_in[1];
    const float* tp_weights    = (const float*)d_in[2];
    const int*   sender_list   = (const int*)d_in[3];
    const int*   receiver_list = (const int*)d_in[4];
    float* out    = (float*)d_out;
    int* row_ptr  = (int*)d_ws;   // 10001 ints, rewritten every launch

    bounds_kernel<<<(N_NODES + 256) / 256, 256, 0, stream>>>(receiver_list, row_ptr);
    imp_tp_kernel<<<N_NODES / 4, 256, 0, stream>>>(
        node_feats, edge_attrs, tp_weights, sender_list, row_ptr, out);
}